// Round 9
// baseline (212.574 us; speedup 1.0000x reference)
//
#include <hip/hip_runtime.h>
#include <hip/hip_bf16.h>

typedef __attribute__((ext_vector_type(8))) short bf16x8;
typedef __attribute__((ext_vector_type(4))) float f32x4;

__device__ __forceinline__ unsigned short f2b(float f) {
    union { float f; unsigned int u; } v; v.f = f;
    unsigned int u = v.u;
    unsigned int r = (u + 0x7FFFu + ((u >> 16) & 1u)) >> 16;  // RNE
    return (unsigned short)r;
}
__device__ __forceinline__ float b2f(unsigned short h) {
    union { unsigned int u; float f; } v; v.u = ((unsigned int)h) << 16;
    return v.f;
}
// packed bf16x2 from two floats
__device__ __forceinline__ unsigned pk2(float a, float b) {
    union { __hip_bfloat162 h; unsigned u; } c;
    c.h = __float22bfloat162_rn(make_float2(a, b));
    return c.u;
}

// Weight prep (coalesced via LDS tiles). WQ pre-scaled by 1/16 (folds softmax
// scale).
__global__ __launch_bounds__(256) void prep_w(
    const float* __restrict__ WQ, const float* __restrict__ WK,
    const float* __restrict__ WV,
    const float* __restrict__ Qb, const float* __restrict__ Kb,
    const float* __restrict__ Vb,
    unsigned short* __restrict__ WQt, unsigned short* __restrict__ WKt,
    unsigned short* __restrict__ WVt,
    unsigned short* __restrict__ Bq, unsigned short* __restrict__ Bk,
    unsigned short* __restrict__ Bv) {
    int b = blockIdx.x, t = threadIdx.x;
    if (b < 288) {
        const float* W; unsigned short* Wt; int h, d0, D; float sc = 1.0f;
        if (b < 128)      { W = WQ; Wt = WQt; h = b >> 4;   d0 = (b & 15) * 64; D = 1024; sc = 0.0625f; }
        else if (b < 256) { int bb = b - 128; W = WK; Wt = WKt; h = bb >> 4; d0 = (bb & 15) * 64; D = 1024; }
        else              { int bb = b - 256; W = WV; Wt = WVt; h = bb >> 2; d0 = (bb & 3) * 64;  D = 256; }
        __shared__ float Ts[32][65];
        int dr = t >> 2, k0 = (t & 3) * 8;
        const float* src = W + (h * D + d0 + dr) * 32 + k0;
        float4 u0 = *(const float4*)src;
        float4 u1 = *(const float4*)(src + 4);
        Ts[k0 + 0][dr] = u0.x; Ts[k0 + 1][dr] = u0.y; Ts[k0 + 2][dr] = u0.z; Ts[k0 + 3][dr] = u0.w;
        Ts[k0 + 4][dr] = u1.x; Ts[k0 + 5][dr] = u1.y; Ts[k0 + 6][dr] = u1.z; Ts[k0 + 7][dr] = u1.w;
        __syncthreads();
        int k = t >> 3, dc = (t & 7) * 8;
        union { unsigned short s[8]; uint4 v; } pk;
#pragma unroll
        for (int i = 0; i < 8; i++) pk.s[i] = f2b(Ts[k][dc + i] * sc);
        *(uint4*)(Wt + (h * 32 + k) * D + d0 + dc) = pk.v;
    } else {
        Bq[t] = f2b(Qb[t] * 0.0625f); Bk[t] = f2b(Kb[t]); Bv[t] = f2b(Vb[t]);
    }
}

// Fused Q/K/V projections: one launch, 768 blocks (3/CU).
__global__ __launch_bounds__(256) void proj_fused(
    const float* __restrict__ x,
    const float* __restrict__ peQ, const float* __restrict__ peK,
    const unsigned short* __restrict__ WQt, const unsigned short* __restrict__ WKt,
    const unsigned short* __restrict__ WVt,
    const unsigned short* __restrict__ Bq, const unsigned short* __restrict__ Bk,
    const unsigned short* __restrict__ Bv,
    unsigned short* __restrict__ Qc, unsigned short* __restrict__ Kc,
    unsigned short* __restrict__ Vtr) {
    __shared__ unsigned short As[64 * 72];
    __shared__ unsigned short Bs[64 * 72];
    int bx = blockIdx.x;
    int which = bx >> 8, bb = bx & 255;
    const float* A1; const unsigned short* Bt; const unsigned short* bias; int K;
    if (which == 0)      { A1 = peQ; Bt = WQt; bias = Bq; K = 1024; }
    else if (which == 1) { A1 = peK; Bt = WKt; bias = Bk; K = 1024; }
    else                 { A1 = peQ; Bt = WVt; bias = Bv; K = 256; }  // A1 unused for V
    int mb = bb & 63, nb = bb >> 6;
    int m0 = mb * 64, n0 = nb * 64;
    int t = threadIdx.x, w = t >> 6, lane = t & 63;
    int ln = lane & 15, q8 = (lane >> 4) * 8;
    int wm = (w >> 1) * 32, wn = (w & 1) * 32;
    int sr = t >> 3, sc = (t & 7) * 8;
    f32x4 acc[2][2];
#pragma unroll
    for (int i = 0; i < 2; i++)
#pragma unroll
        for (int j = 0; j < 2; j++) acc[i][j] = (f32x4){0.f, 0.f, 0.f, 0.f};
    for (int kb = 0; kb < K; kb += 64) {
#pragma unroll
        for (int half = 0; half < 2; half++) {
            int r = sr + half * 32;
            int c = kb + sc;
            const float* ap = (c < 256)
                ? (x + (m0 + r) * 256 + c)
                : (A1 + (m0 + r) * 768 + (c - 256));
            float4 u0 = *(const float4*)ap;
            float4 u1 = *(const float4*)(ap + 4);
            union { unsigned u[4]; uint4 v; } pk;
            pk.u[0] = pk2(u0.x, u0.y); pk.u[1] = pk2(u0.z, u0.w);
            pk.u[2] = pk2(u1.x, u1.y); pk.u[3] = pk2(u1.z, u1.w);
            *(uint4*)&As[r * 72 + sc] = pk.v;
            *(uint4*)&Bs[r * 72 + sc] = *(const uint4*)(Bt + (n0 + r) * K + c);
        }
        __syncthreads();
#pragma unroll
        for (int ks = 0; ks < 64; ks += 32) {
            bf16x8 a[2], b[2];
#pragma unroll
            for (int i = 0; i < 2; i++) {
                a[i] = *(const bf16x8*)&As[(wm + i * 16 + ln) * 72 + ks + q8];
                b[i] = *(const bf16x8*)&Bs[(wn + i * 16 + ln) * 72 + ks + q8];
            }
#pragma unroll
            for (int i = 0; i < 2; i++)
#pragma unroll
                for (int j = 0; j < 2; j++)
                    acc[i][j] = __builtin_amdgcn_mfma_f32_16x16x32_bf16(a[i], b[j], acc[i][j], 0, 0, 0);
        }
        __syncthreads();
    }
#pragma unroll
    for (int j = 0; j < 2; j++) {
        int ncol = n0 + wn + j * 16 + ln;
        float bv = b2f(bias[ncol]);
#pragma unroll
        for (int i = 0; i < 2; i++) {
            int rbase = m0 + wm + i * 16 + ((lane >> 4) * 4);
            if (which < 2) {
                unsigned short* C = which ? Kc : Qc;
#pragma unroll
                for (int r = 0; r < 4; r++)
                    C[(rbase + r) * 256 + ncol] = f2b(acc[i][j][r] + bv);
            } else {
                unsigned lo = pk2(acc[i][j][0] + bv, acc[i][j][1] + bv);
                unsigned hi = pk2(acc[i][j][2] + bv, acc[i][j][3] + bv);
                uint2 vv; vv.x = lo; vv.y = hi;
                *(uint2*)(Vtr + ncol * 4096 + rbase) = vv;
            }
        }
    }
}

// Flash attention, fixed-shift softmax, register-prefetched K/V (distance-1
// double buffer). Block = (head, 32 q), 4 waves = 4-way key split. Zero
// cross-lane ops in the loop; vectorized l accumulator (breaks the serial
// FP-add chain). Linear LDS combine at the end.
__global__ __launch_bounds__(256, 3) void attn_kernel(
    const unsigned short* __restrict__ Qc,
    const unsigned short* __restrict__ Kc,
    const unsigned short* __restrict__ Vt,
    unsigned short* __restrict__ Xc) {
    __shared__ float Om[4][32][33];   // wave, d, q
    __shared__ float Ls[4][32];       // wave, q
    int head = blockIdx.x >> 7;
    int qb = blockIdx.x & 127;
    int t = threadIdx.x, w = t >> 6, lane = t & 63;
    int ln = lane & 15, quad = lane >> 4, q8 = quad * 8;
    int q0 = qb * 32;
    bf16x8 qfv[2];
#pragma unroll
    for (int qf = 0; qf < 2; qf++)
        qfv[qf] = *(const bf16x8*)(Qc + (q0 + qf * 16 + ln) * 256 + head * 32 + q8);
    const unsigned short* kbase[4];
#pragma unroll
    for (int kt = 0; kt < 4; kt++) {
        int key = 8 * (ln >> 2) + (ln & 3) + 4 * (kt & 1) + 32 * (kt >> 1);
        kbase[kt] = Kc + key * 256 + head * 32 + q8;
    }
    const unsigned short* vb0 = Vt + (head * 32 + ln) * 4096 + q8;
    const unsigned short* vb1 = Vt + (head * 32 + 16 + ln) * 4096 + q8;
    f32x4 o[2][2];
#pragma unroll
    for (int qf = 0; qf < 2; qf++)
#pragma unroll
        for (int hh = 0; hh < 2; hh++) o[qf][hh] = (f32x4){0.f, 0.f, 0.f, 0.f};
    const f32x4 z = {0.f, 0.f, 0.f, 0.f};
    f32x4 lacc[2]; lacc[0] = z; lacc[1] = z;
    int base = w * 1024;
    // current-tile registers (tile 0)
    bf16x8 k0 = *(const bf16x8*)(kbase[0] + base * 256);
    bf16x8 k1 = *(const bf16x8*)(kbase[1] + base * 256);
    bf16x8 k2 = *(const bf16x8*)(kbase[2] + base * 256);
    bf16x8 k3 = *(const bf16x8*)(kbase[3] + base * 256);
    bf16x8 v0 = *(const bf16x8*)(vb0 + base);
    bf16x8 v1 = *(const bf16x8*)(vb0 + base + 32);
    bf16x8 v2 = *(const bf16x8*)(vb1 + base);
    bf16x8 v3 = *(const bf16x8*)(vb1 + base + 32);
#pragma unroll 1
    for (int it = 0; it < 16; it++) {
        int nit = (it < 15) ? (it + 1) : 15;   // clamp: last iter reloads tile 15
        int nkb = base + nit * 64;
        bf16x8 nk0 = *(const bf16x8*)(kbase[0] + nkb * 256);
        bf16x8 nk1 = *(const bf16x8*)(kbase[1] + nkb * 256);
        bf16x8 nk2 = *(const bf16x8*)(kbase[2] + nkb * 256);
        bf16x8 nk3 = *(const bf16x8*)(kbase[3] + nkb * 256);
        bf16x8 nv0 = *(const bf16x8*)(vb0 + nkb);
        bf16x8 nv1 = *(const bf16x8*)(vb0 + nkb + 32);
        bf16x8 nv2 = *(const bf16x8*)(vb1 + nkb);
        bf16x8 nv3 = *(const bf16x8*)(vb1 + nkb + 32);
#pragma unroll
        for (int qf = 0; qf < 2; qf++) {
            f32x4 s0 = __builtin_amdgcn_mfma_f32_16x16x32_bf16(k0, qfv[qf], z, 0, 0, 0);
            f32x4 s1 = __builtin_amdgcn_mfma_f32_16x16x32_bf16(k1, qfv[qf], z, 0, 0, 0);
            f32x4 s2 = __builtin_amdgcn_mfma_f32_16x16x32_bf16(k2, qfv[qf], z, 0, 0, 0);
            f32x4 s3 = __builtin_amdgcn_mfma_f32_16x16x32_bf16(k3, qfv[qf], z, 0, 0, 0);
            float p0[4], p1[4], p2[4], p3[4];
#pragma unroll
            for (int r = 0; r < 4; r++) {
                p0[r] = __expf(s0[r]); p1[r] = __expf(s1[r]);
                p2[r] = __expf(s2[r]); p3[r] = __expf(s3[r]);
            }
            f32x4 ps;
#pragma unroll
            for (int r = 0; r < 4; r++) ps[r] = (p0[r] + p1[r]) + (p2[r] + p3[r]);
            lacc[qf] += ps;
            union { unsigned u[4]; bf16x8 v; } b0, b1;
            b0.u[0] = pk2(p0[0], p0[1]); b0.u[1] = pk2(p0[2], p0[3]);
            b0.u[2] = pk2(p1[0], p1[1]); b0.u[3] = pk2(p1[2], p1[3]);
            b1.u[0] = pk2(p2[0], p2[1]); b1.u[1] = pk2(p2[2], p2[3]);
            b1.u[2] = pk2(p3[0], p3[1]); b1.u[3] = pk2(p3[2], p3[3]);
            o[qf][0] = __builtin_amdgcn_mfma_f32_16x16x32_bf16(v0, b0.v, o[qf][0], 0, 0, 0);
            o[qf][0] = __builtin_amdgcn_mfma_f32_16x16x32_bf16(v1, b1.v, o[qf][0], 0, 0, 0);
            o[qf][1] = __builtin_amdgcn_mfma_f32_16x16x32_bf16(v2, b0.v, o[qf][1], 0, 0, 0);
            o[qf][1] = __builtin_amdgcn_mfma_f32_16x16x32_bf16(v3, b1.v, o[qf][1], 0, 0, 0);
        }
        k0 = nk0; k1 = nk1; k2 = nk2; k3 = nk3;
        v0 = nv0; v1 = nv1; v2 = nv2; v3 = nv3;
    }
#pragma unroll
    for (int qf = 0; qf < 2; qf++) {
        float lts = (lacc[qf][0] + lacc[qf][1]) + (lacc[qf][2] + lacc[qf][3]);
        lts += __shfl_xor(lts, 16, 64);
        lts += __shfl_xor(lts, 32, 64);
#pragma unroll
        for (int r = 0; r < 4; r++) {
            Om[w][quad * 4 + r][qf * 16 + ln] = o[qf][0][r];
            Om[w][16 + quad * 4 + r][qf * 16 + ln] = o[qf][1][r];
        }
        if (quad == 0) Ls[w][qf * 16 + ln] = lts;
    }
    __syncthreads();
    // combine (linear: shared implicit shift): q = t&31, d = (t>>5)*4
    int q = t & 31, d = (t >> 5) * 4;
    float num[4] = {0.f, 0.f, 0.f, 0.f};
    float den = 0.f;
#pragma unroll
    for (int w2 = 0; w2 < 4; w2++) {
        den += Ls[w2][q];
#pragma unroll
        for (int i = 0; i < 4; i++) num[i] += Om[w2][d + i][q];
    }
    float inv = 1.f / den;
    uint2 outv;
    outv.x = pk2(num[0] * inv, num[1] * inv);
    outv.y = pk2(num[2] * inv, num[3] * inv);
    *(uint2*)(Xc + (q0 + q) * 256 + head * 32 + d) = outv;
}

// Final GEMM: d_out[4096][256] f32 = Xc(bf16) @ lin_w^T + lin_b.
__global__ __launch_bounds__(256) void gemm_out(
    const unsigned short* __restrict__ A,
    const float* __restrict__ LW,
    const float* __restrict__ Lb,
    float* __restrict__ C) {
    __shared__ unsigned short As[64 * 72];
    __shared__ unsigned short Bs[64 * 72];
    int mb = blockIdx.x & 63, nb = blockIdx.x >> 6;
    int m0 = mb * 64, n0 = nb * 64;
    int t = threadIdx.x, w = t >> 6, lane = t & 63;
    int ln = lane & 15, q8 = (lane >> 4) * 8;
    int wm = (w >> 1) * 32, wn = (w & 1) * 32;
    int sr = t >> 3, sc = (t & 7) * 8;
    f32x4 acc[2][2];
#pragma unroll
    for (int i = 0; i < 2; i++)
#pragma unroll
        for (int j = 0; j < 2; j++) acc[i][j] = (f32x4){0.f, 0.f, 0.f, 0.f};
    for (int kb = 0; kb < 256; kb += 64) {
#pragma unroll
        for (int half = 0; half < 2; half++) {
            int r = sr + half * 32;
            int c = kb + sc;
            *(uint4*)&As[r * 72 + sc] = *(const uint4*)(A + (m0 + r) * 256 + c);
            const float* bp = LW + (n0 + r) * 256 + c;
            float4 u0 = *(const float4*)bp;
            float4 u1 = *(const float4*)(bp + 4);
            union { unsigned u[4]; uint4 v; } pk;
            pk.u[0] = pk2(u0.x, u0.y); pk.u[1] = pk2(u0.z, u0.w);
            pk.u[2] = pk2(u1.x, u1.y); pk.u[3] = pk2(u1.z, u1.w);
            *(uint4*)&Bs[r * 72 + sc] = pk.v;
        }
        __syncthreads();
#pragma unroll
        for (int ks = 0; ks < 64; ks += 32) {
            bf16x8 a[2], b[2];
#pragma unroll
            for (int i = 0; i < 2; i++) {
                a[i] = *(const bf16x8*)&As[(wm + i * 16 + ln) * 72 + ks + q8];
                b[i] = *(const bf16x8*)&Bs[(wn + i * 16 + ln) * 72 + ks + q8];
            }
#pragma unroll
            for (int i = 0; i < 2; i++)
#pragma unroll
                for (int j = 0; j < 2; j++)
                    acc[i][j] = __builtin_amdgcn_mfma_f32_16x16x32_bf16(a[i], b[j], acc[i][j], 0, 0, 0);
        }
        __syncthreads();
    }
#pragma unroll
    for (int j = 0; j < 2; j++) {
        int ncol = n0 + wn + j * 16 + ln;
        float bv = Lb[ncol];
#pragma unroll
        for (int i = 0; i < 2; i++) {
            int rbase = m0 + wm + i * 16 + ((lane >> 4) * 4);
#pragma unroll
            for (int r = 0; r < 4; r++)
                C[(rbase + r) * 256 + ncol] = acc[i][j][r] + bv;
        }
    }
}

extern "C" void kernel_launch(void* const* d_in, const int* in_sizes, int n_in,
                              void* d_out, int out_size, void* d_ws, size_t ws_size,
                              hipStream_t stream) {
    const float* input_x = (const float*)d_in[0];
    const float* pe_Q    = (const float*)d_in[1];
    const float* pe_K    = (const float*)d_in[2];
    // d_in[3] = A (unused)
    const float* WQ = (const float*)d_in[4];
    const float* WK = (const float*)d_in[5];
    const float* WV = (const float*)d_in[6];
    const float* Qb = (const float*)d_in[7];
    const float* Kb = (const float*)d_in[8];
    const float* Vb = (const float*)d_in[9];
    const float* lw = (const float*)d_in[10];
    const float* lb = (const float*)d_in[11];

    unsigned short* ws = (unsigned short*)d_ws;
    unsigned short* WQt = ws;                  // 262144
    unsigned short* WKt = WQt + 262144;        // 262144
    unsigned short* WVt = WKt + 262144;        // 65536
    unsigned short* Bq  = WVt + 65536;         // 256 x3
    unsigned short* Bk  = Bq + 256;
    unsigned short* Bv  = Bk + 256;
    unsigned short* Qc  = Bv + 256;            // 4096*256
    unsigned short* Kc  = Qc + 1048576;
    unsigned short* Vtr = Kc + 1048576;        // 256*4096
    unsigned short* Xc  = Vtr + 1048576;       // 4096*256

    prep_w<<<dim3(289), dim3(256), 0, stream>>>(WQ, WK, WV, Qb, Kb, Vb,
                                                WQt, WKt, WVt, Bq, Bk, Bv);
    proj_fused<<<dim3(768), dim3(256), 0, stream>>>(input_x, pe_Q, pe_K,
                                                    WQt, WKt, WVt, Bq, Bk, Bv,
                                                    Qc, Kc, Vtr);
    attn_kernel<<<dim3(1024), dim3(256), 0, stream>>>(Qc, Kc, Vtr, Xc);
    gemm_out<<<dim3(256), dim3(256), 0, stream>>>(Xc, lw, lb, (float*)d_out);
}

// Round 10
// 181.936 us; speedup vs baseline: 1.1684x; 1.1684x over previous
//
#include <hip/hip_runtime.h>
#include <hip/hip_bf16.h>

typedef __attribute__((ext_vector_type(8))) short bf16x8;
typedef __attribute__((ext_vector_type(4))) float f32x4;

__device__ __forceinline__ unsigned short f2b(float f) {
    union { float f; unsigned int u; } v; v.f = f;
    unsigned int u = v.u;
    unsigned int r = (u + 0x7FFFu + ((u >> 16) & 1u)) >> 16;  // RNE
    return (unsigned short)r;
}
__device__ __forceinline__ float b2f(unsigned short h) {
    union { unsigned int u; float f; } v; v.u = ((unsigned int)h) << 16;
    return v.f;
}
// packed bf16x2 from two floats
__device__ __forceinline__ unsigned pk2(float a, float b) {
    union { __hip_bfloat162 h; unsigned u; } c;
    c.h = __float22bfloat162_rn(make_float2(a, b));
    return c.u;
}

// Blocked KV layout: per (head h, key-tile T of 64): 4096 shorts (8 KB) at
// KV + (h*64+T)*4096. chunk c (0..7) = 512 shorts; lane L = 8 shorts.
// c0..3 = K-fragments (QK^T A-operand, keys permuted); c4..7 = V-fragments.

// Weight prep (coalesced via LDS tiles). WQ pre-scaled by 1/16 (folds softmax
// scale).
__global__ __launch_bounds__(256) void prep_w(
    const float* __restrict__ WQ, const float* __restrict__ WK,
    const float* __restrict__ WV,
    const float* __restrict__ Qb, const float* __restrict__ Kb,
    const float* __restrict__ Vb,
    unsigned short* __restrict__ WQt, unsigned short* __restrict__ WKt,
    unsigned short* __restrict__ WVt,
    unsigned short* __restrict__ Bq, unsigned short* __restrict__ Bk,
    unsigned short* __restrict__ Bv) {
    int b = blockIdx.x, t = threadIdx.x;
    if (b < 288) {
        const float* W; unsigned short* Wt; int h, d0, D; float sc = 1.0f;
        if (b < 128)      { W = WQ; Wt = WQt; h = b >> 4;   d0 = (b & 15) * 64; D = 1024; sc = 0.0625f; }
        else if (b < 256) { int bb = b - 128; W = WK; Wt = WKt; h = bb >> 4; d0 = (bb & 15) * 64; D = 1024; }
        else              { int bb = b - 256; W = WV; Wt = WVt; h = bb >> 2; d0 = (bb & 3) * 64;  D = 256; }
        __shared__ float Ts[32][65];
        int dr = t >> 2, k0 = (t & 3) * 8;
        const float* src = W + (h * D + d0 + dr) * 32 + k0;
        float4 u0 = *(const float4*)src;
        float4 u1 = *(const float4*)(src + 4);
        Ts[k0 + 0][dr] = u0.x; Ts[k0 + 1][dr] = u0.y; Ts[k0 + 2][dr] = u0.z; Ts[k0 + 3][dr] = u0.w;
        Ts[k0 + 4][dr] = u1.x; Ts[k0 + 5][dr] = u1.y; Ts[k0 + 6][dr] = u1.z; Ts[k0 + 7][dr] = u1.w;
        __syncthreads();
        int k = t >> 3, dc = (t & 7) * 8;
        union { unsigned short s[8]; uint4 v; } pk;
#pragma unroll
        for (int i = 0; i < 8; i++) pk.s[i] = f2b(Ts[k][dc + i] * sc);
        *(uint4*)(Wt + (h * 32 + k) * D + d0 + dc) = pk.v;
    } else {
        Bq[t] = f2b(Qb[t] * 0.0625f); Bk[t] = f2b(Kb[t]); Bv[t] = f2b(Vb[t]);
    }
}

// Fused Q/K/V projections: one launch, 768 blocks (3/CU).
// Q -> Qc row-major; K and V -> blocked KV buffer (attn-native layout).
__global__ __launch_bounds__(256) void proj_fused(
    const float* __restrict__ x,
    const float* __restrict__ peQ, const float* __restrict__ peK,
    const unsigned short* __restrict__ WQt, const unsigned short* __restrict__ WKt,
    const unsigned short* __restrict__ WVt,
    const unsigned short* __restrict__ Bq, const unsigned short* __restrict__ Bk,
    const unsigned short* __restrict__ Bv,
    unsigned short* __restrict__ Qc, unsigned short* __restrict__ KV) {
    __shared__ unsigned short As[64 * 72];
    __shared__ unsigned short Bs[64 * 72];
    int bx = blockIdx.x;
    int which = bx >> 8, bb = bx & 255;
    const float* A1; const unsigned short* Bt; const unsigned short* bias; int K;
    if (which == 0)      { A1 = peQ; Bt = WQt; bias = Bq; K = 1024; }
    else if (which == 1) { A1 = peK; Bt = WKt; bias = Bk; K = 1024; }
    else                 { A1 = peQ; Bt = WVt; bias = Bv; K = 256; }  // A1 unused for V
    int mb = bb & 63, nb = bb >> 6;
    int m0 = mb * 64, n0 = nb * 64;
    int t = threadIdx.x, w = t >> 6, lane = t & 63;
    int ln = lane & 15, q8 = (lane >> 4) * 8;
    int wm = (w >> 1) * 32, wn = (w & 1) * 32;
    int sr = t >> 3, sc = (t & 7) * 8;
    f32x4 acc[2][2];
#pragma unroll
    for (int i = 0; i < 2; i++)
#pragma unroll
        for (int j = 0; j < 2; j++) acc[i][j] = (f32x4){0.f, 0.f, 0.f, 0.f};
    for (int kb = 0; kb < K; kb += 64) {
#pragma unroll
        for (int half = 0; half < 2; half++) {
            int r = sr + half * 32;
            int c = kb + sc;
            const float* ap = (c < 256)
                ? (x + (m0 + r) * 256 + c)
                : (A1 + (m0 + r) * 768 + (c - 256));
            float4 u0 = *(const float4*)ap;
            float4 u1 = *(const float4*)(ap + 4);
            union { unsigned u[4]; uint4 v; } pk;
            pk.u[0] = pk2(u0.x, u0.y); pk.u[1] = pk2(u0.z, u0.w);
            pk.u[2] = pk2(u1.x, u1.y); pk.u[3] = pk2(u1.z, u1.w);
            *(uint4*)&As[r * 72 + sc] = pk.v;
            *(uint4*)&Bs[r * 72 + sc] = *(const uint4*)(Bt + (n0 + r) * K + c);
        }
        __syncthreads();
#pragma unroll
        for (int ks = 0; ks < 64; ks += 32) {
            bf16x8 a[2], b[2];
#pragma unroll
            for (int i = 0; i < 2; i++) {
                a[i] = *(const bf16x8*)&As[(wm + i * 16 + ln) * 72 + ks + q8];
                b[i] = *(const bf16x8*)&Bs[(wn + i * 16 + ln) * 72 + ks + q8];
            }
#pragma unroll
            for (int i = 0; i < 2; i++)
#pragma unroll
                for (int j = 0; j < 2; j++)
                    acc[i][j] = __builtin_amdgcn_mfma_f32_16x16x32_bf16(a[i], b[j], acc[i][j], 0, 0, 0);
        }
        __syncthreads();
    }
#pragma unroll
    for (int j = 0; j < 2; j++) {
        int ncol = n0 + wn + j * 16 + ln;
        float bv = b2f(bias[ncol]);
        int h2 = ncol >> 5, din = ncol & 31;
#pragma unroll
        for (int i = 0; i < 2; i++) {
            int rbase = m0 + wm + i * 16 + ((lane >> 4) * 4);
            if (which == 0) {
#pragma unroll
                for (int r = 0; r < 4; r++)
                    Qc[(rbase + r) * 256 + ncol] = f2b(acc[i][j][r] + bv);
            } else if (which == 1) {
                // blocked K-fragment store (scalar scatter, same cost as row-major)
#pragma unroll
                for (int r = 0; r < 4; r++) {
                    int key = rbase + r;
                    int T2 = key >> 6, k6 = key & 63;
                    int kt = ((k6 >> 2) & 1) + ((k6 >> 4) & 2);
                    int ln2 = ((k6 >> 3) & 3) * 4 + (k6 & 3);
                    int addr = (h2 * 64 + T2) * 4096 + kt * 512
                             + ((din >> 3) * 16 + ln2) * 8 + (din & 7);
                    KV[addr] = f2b(acc[i][j][r] + bv);
                }
            } else {
                // blocked V-fragment store: 4 consecutive keys -> 4 consecutive
                // shorts in one lane slot (uint2)
                int key = rbase;
                int T2 = key >> 6, k6 = key & 63;
                int chunk = 4 + ((din >> 4) << 1) + ((k6 >> 5) & 1);
                int lane2 = ((k6 >> 3) & 3) * 16 + (din & 15);
                int addr = (h2 * 64 + T2) * 4096 + chunk * 512 + lane2 * 8 + (k6 & 7);
                uint2 vv;
                vv.x = pk2(acc[i][j][0] + bv, acc[i][j][1] + bv);
                vv.y = pk2(acc[i][j][2] + bv, acc[i][j][3] + bv);
                *(uint2*)(KV + addr) = vv;
            }
        }
    }
}

// Flash attention, fixed-shift softmax, blocked-KV streaming loads.
// Block = (head, 32 q), 4 waves = 4-way key split; wave w reads tiles
// w*16..w*16+15 as contiguous 8-KB records. Distance-1 register prefetch.
__global__ __launch_bounds__(256, 4) void attn_kernel(
    const unsigned short* __restrict__ Qc,
    const unsigned short* __restrict__ KV,
    unsigned short* __restrict__ Xc) {
    __shared__ float Om[4][32][33];   // wave, d, q
    __shared__ float Ls[4][32];       // wave, q
    int head = blockIdx.x >> 7;
    int qb = blockIdx.x & 127;
    int t = threadIdx.x, w = t >> 6, lane = t & 63;
    int ln = lane & 15, quad = lane >> 4, q8 = quad * 8;
    int q0 = qb * 32;
    bf16x8 qfv[2];
#pragma unroll
    for (int qf = 0; qf < 2; qf++)
        qfv[qf] = *(const bf16x8*)(Qc + (q0 + qf * 16 + ln) * 256 + head * 32 + q8);
    const unsigned short* kv = KV + (head * 64 + w * 16) * 4096 + lane * 8;
    f32x4 o[2][2];
#pragma unroll
    for (int qf = 0; qf < 2; qf++)
#pragma unroll
        for (int hh = 0; hh < 2; hh++) o[qf][hh] = (f32x4){0.f, 0.f, 0.f, 0.f};
    const f32x4 z = {0.f, 0.f, 0.f, 0.f};
    f32x4 lacc[2]; lacc[0] = z; lacc[1] = z;
    // current-tile registers (tile 0)
    bf16x8 k0 = *(const bf16x8*)(kv + 0);
    bf16x8 k1 = *(const bf16x8*)(kv + 512);
    bf16x8 k2 = *(const bf16x8*)(kv + 1024);
    bf16x8 k3 = *(const bf16x8*)(kv + 1536);
    bf16x8 v0 = *(const bf16x8*)(kv + 2048);
    bf16x8 v1 = *(const bf16x8*)(kv + 2560);
    bf16x8 v2 = *(const bf16x8*)(kv + 3072);
    bf16x8 v3 = *(const bf16x8*)(kv + 3584);
#pragma unroll 1
    for (int it = 0; it < 16; it++) {
        int nit = (it < 15) ? (it + 1) : 15;   // clamp: last iter reloads tile 15
        const unsigned short* nkv = kv + nit * 4096;
        bf16x8 nk0 = *(const bf16x8*)(nkv + 0);
        bf16x8 nk1 = *(const bf16x8*)(nkv + 512);
        bf16x8 nk2 = *(const bf16x8*)(nkv + 1024);
        bf16x8 nk3 = *(const bf16x8*)(nkv + 1536);
        bf16x8 nv0 = *(const bf16x8*)(nkv + 2048);
        bf16x8 nv1 = *(const bf16x8*)(nkv + 2560);
        bf16x8 nv2 = *(const bf16x8*)(nkv + 3072);
        bf16x8 nv3 = *(const bf16x8*)(nkv + 3584);
#pragma unroll
        for (int qf = 0; qf < 2; qf++) {
            f32x4 s0 = __builtin_amdgcn_mfma_f32_16x16x32_bf16(k0, qfv[qf], z, 0, 0, 0);
            f32x4 s1 = __builtin_amdgcn_mfma_f32_16x16x32_bf16(k1, qfv[qf], z, 0, 0, 0);
            f32x4 s2 = __builtin_amdgcn_mfma_f32_16x16x32_bf16(k2, qfv[qf], z, 0, 0, 0);
            f32x4 s3 = __builtin_amdgcn_mfma_f32_16x16x32_bf16(k3, qfv[qf], z, 0, 0, 0);
            float p0[4], p1[4], p2[4], p3[4];
#pragma unroll
            for (int r = 0; r < 4; r++) {
                p0[r] = __expf(s0[r]); p1[r] = __expf(s1[r]);
                p2[r] = __expf(s2[r]); p3[r] = __expf(s3[r]);
            }
            f32x4 ps;
#pragma unroll
            for (int r = 0; r < 4; r++) ps[r] = (p0[r] + p1[r]) + (p2[r] + p3[r]);
            lacc[qf] += ps;
            union { unsigned u[4]; bf16x8 v; } b0, b1;
            b0.u[0] = pk2(p0[0], p0[1]); b0.u[1] = pk2(p0[2], p0[3]);
            b0.u[2] = pk2(p1[0], p1[1]); b0.u[3] = pk2(p1[2], p1[3]);
            b1.u[0] = pk2(p2[0], p2[1]); b1.u[1] = pk2(p2[2], p2[3]);
            b1.u[2] = pk2(p3[0], p3[1]); b1.u[3] = pk2(p3[2], p3[3]);
            o[qf][0] = __builtin_amdgcn_mfma_f32_16x16x32_bf16(v0, b0.v, o[qf][0], 0, 0, 0);
            o[qf][0] = __builtin_amdgcn_mfma_f32_16x16x32_bf16(v1, b1.v, o[qf][0], 0, 0, 0);
            o[qf][1] = __builtin_amdgcn_mfma_f32_16x16x32_bf16(v2, b0.v, o[qf][1], 0, 0, 0);
            o[qf][1] = __builtin_amdgcn_mfma_f32_16x16x32_bf16(v3, b1.v, o[qf][1], 0, 0, 0);
        }
        k0 = nk0; k1 = nk1; k2 = nk2; k3 = nk3;
        v0 = nv0; v1 = nv1; v2 = nv2; v3 = nv3;
    }
#pragma unroll
    for (int qf = 0; qf < 2; qf++) {
        float lts = (lacc[qf][0] + lacc[qf][1]) + (lacc[qf][2] + lacc[qf][3]);
        lts += __shfl_xor(lts, 16, 64);
        lts += __shfl_xor(lts, 32, 64);
#pragma unroll
        for (int r = 0; r < 4; r++) {
            Om[w][quad * 4 + r][qf * 16 + ln] = o[qf][0][r];
            Om[w][16 + quad * 4 + r][qf * 16 + ln] = o[qf][1][r];
        }
        if (quad == 0) Ls[w][qf * 16 + ln] = lts;
    }
    __syncthreads();
    // combine (linear: shared implicit shift): q = t&31, d = (t>>5)*4
    int q = t & 31, d = (t >> 5) * 4;
    float num[4] = {0.f, 0.f, 0.f, 0.f};
    float den = 0.f;
#pragma unroll
    for (int w2 = 0; w2 < 4; w2++) {
        den += Ls[w2][q];
#pragma unroll
        for (int i = 0; i < 4; i++) num[i] += Om[w2][d + i][q];
    }
    float inv = 1.f / den;
    uint2 outv;
    outv.x = pk2(num[0] * inv, num[1] * inv);
    outv.y = pk2(num[2] * inv, num[3] * inv);
    *(uint2*)(Xc + (q0 + q) * 256 + head * 32 + d) = outv;
}

// Final GEMM: d_out[4096][256] f32 = Xc(bf16) @ lin_w^T + lin_b.
__global__ __launch_bounds__(256) void gemm_out(
    const unsigned short* __restrict__ A,
    const float* __restrict__ LW,
    const float* __restrict__ Lb,
    float* __restrict__ C) {
    __shared__ unsigned short As[64 * 72];
    __shared__ unsigned short Bs[64 * 72];
    int mb = blockIdx.x & 63, nb = blockIdx.x >> 6;
    int m0 = mb * 64, n0 = nb * 64;
    int t = threadIdx.x, w = t >> 6, lane = t & 63;
    int ln = lane & 15, q8 = (lane >> 4) * 8;
    int wm = (w >> 1) * 32, wn = (w & 1) * 32;
    int sr = t >> 3, sc = (t & 7) * 8;
    f32x4 acc[2][2];
#pragma unroll
    for (int i = 0; i < 2; i++)
#pragma unroll
        for (int j = 0; j < 2; j++) acc[i][j] = (f32x4){0.f, 0.f, 0.f, 0.f};
    for (int kb = 0; kb < 256; kb += 64) {
#pragma unroll
        for (int half = 0; half < 2; half++) {
            int r = sr + half * 32;
            int c = kb + sc;
            *(uint4*)&As[r * 72 + sc] = *(const uint4*)(A + (m0 + r) * 256 + c);
            const float* bp = LW + (n0 + r) * 256 + c;
            float4 u0 = *(const float4*)bp;
            float4 u1 = *(const float4*)(bp + 4);
            union { unsigned u[4]; uint4 v; } pk;
            pk.u[0] = pk2(u0.x, u0.y); pk.u[1] = pk2(u0.z, u0.w);
            pk.u[2] = pk2(u1.x, u1.y); pk.u[3] = pk2(u1.z, u1.w);
            *(uint4*)&Bs[r * 72 + sc] = pk.v;
        }
        __syncthreads();
#pragma unroll
        for (int ks = 0; ks < 64; ks += 32) {
            bf16x8 a[2], b[2];
#pragma unroll
            for (int i = 0; i < 2; i++) {
                a[i] = *(const bf16x8*)&As[(wm + i * 16 + ln) * 72 + ks + q8];
                b[i] = *(const bf16x8*)&Bs[(wn + i * 16 + ln) * 72 + ks + q8];
            }
#pragma unroll
            for (int i = 0; i < 2; i++)
#pragma unroll
                for (int j = 0; j < 2; j++)
                    acc[i][j] = __builtin_amdgcn_mfma_f32_16x16x32_bf16(a[i], b[j], acc[i][j], 0, 0, 0);
        }
        __syncthreads();
    }
#pragma unroll
    for (int j = 0; j < 2; j++) {
        int ncol = n0 + wn + j * 16 + ln;
        float bv = Lb[ncol];
#pragma unroll
        for (int i = 0; i < 2; i++) {
            int rbase = m0 + wm + i * 16 + ((lane >> 4) * 4);
#pragma unroll
            for (int r = 0; r < 4; r++)
                C[(rbase + r) * 256 + ncol] = acc[i][j][r] + bv;
        }
    }
}

extern "C" void kernel_launch(void* const* d_in, const int* in_sizes, int n_in,
                              void* d_out, int out_size, void* d_ws, size_t ws_size,
                              hipStream_t stream) {
    const float* input_x = (const float*)d_in[0];
    const float* pe_Q    = (const float*)d_in[1];
    const float* pe_K    = (const float*)d_in[2];
    // d_in[3] = A (unused)
    const float* WQ = (const float*)d_in[4];
    const float* WK = (const float*)d_in[5];
    const float* WV = (const float*)d_in[6];
    const float* Qb = (const float*)d_in[7];
    const float* Kb = (const float*)d_in[8];
    const float* Vb = (const float*)d_in[9];
    const float* lw = (const float*)d_in[10];
    const float* lb = (const float*)d_in[11];

    unsigned short* ws = (unsigned short*)d_ws;
    unsigned short* WQt = ws;                  // 262144
    unsigned short* WKt = WQt + 262144;        // 262144
    unsigned short* WVt = WKt + 262144;        // 65536
    unsigned short* Bq  = WVt + 65536;         // 256 x3
    unsigned short* Bk  = Bq + 256;
    unsigned short* Bv  = Bk + 256;
    unsigned short* Qc  = Bv + 256;            // 4096*256
    unsigned short* KVb = Qc + 1048576;        // 8*64*4096 = 2097152
    unsigned short* Xc  = KVb + 2097152;       // 4096*256

    prep_w<<<dim3(289), dim3(256), 0, stream>>>(WQ, WK, WV, Qb, Kb, Vb,
                                                WQt, WKt, WVt, Bq, Bk, Bv);
    proj_fused<<<dim3(768), dim3(256), 0, stream>>>(input_x, pe_Q, pe_K,
                                                    WQt, WKt, WVt, Bq, Bk, Bv,
                                                    Qc, KVb);
    attn_kernel<<<dim3(1024), dim3(256), 0, stream>>>(Qc, KVb, Xc);
    gemm_out<<<dim3(256), dim3(256), 0, stream>>>(Xc, lw, lb, (float*)d_out);
}